// Round 1
// baseline (4117.209 us; speedup 1.0000x reference)
//
#include <hip/hip_runtime.h>
#include <hip/hip_bf16.h>
#include <cstdint>
#include <cstddef>

// ---------------------------------------------------------------------------
// GPT-2 forward (L=4, B=2, T=1024, C=768, H=12, V=50257) on gfx950.
// Strategy: bf16 MFMA GEMMs (fp32 accum), fp32 residual stream, fp32 softmax.
// ---------------------------------------------------------------------------

typedef __bf16 bf16x8 __attribute__((ext_vector_type(8)));
typedef float floatx4 __attribute__((ext_vector_type(4)));

__device__ inline float bf2f(uint16_t h) {
    union { uint32_t u; float f; } x; x.u = ((uint32_t)h) << 16; return x.f;
}
__device__ inline uint16_t f2bf(float f) {
    union { float f; uint32_t u; } x; x.f = f;
    uint32_t u = x.u;
    uint32_t r = (u + 0x7fffu + ((u >> 16) & 1u)) >> 16;   // RNE
    return (uint16_t)r;
}
__device__ inline float asf(uint32_t u) {
    union { uint32_t u; float f; } x; x.u = u; return x.f;
}

// ---------------------------------------------------------------------------
// Weight transpose + fp32->bf16 convert: in fp32 [K,N] -> out bf16 [Npad,K].
// Zero-fills n in [N, Npad). blockIdx.z = layer.
// ---------------------------------------------------------------------------
__global__ void transpose_cvt(const float* __restrict__ in, uint16_t* __restrict__ out,
                              int K, int N, size_t in_lstride, size_t out_lstride) {
    __shared__ float tile[32][33];
    in  += (size_t)blockIdx.z * in_lstride;
    out += (size_t)blockIdx.z * out_lstride;
    int n0 = blockIdx.x * 32, k0 = blockIdx.y * 32;
    int tx = threadIdx.x, ty = threadIdx.y;
#pragma unroll
    for (int i = 0; i < 4; ++i) {
        int k = k0 + ty + i * 8;
        int n = n0 + tx;
        tile[ty + i * 8][tx] = (n < N) ? in[(size_t)k * N + n] : 0.f;
    }
    __syncthreads();
#pragma unroll
    for (int i = 0; i < 4; ++i) {
        int n = n0 + ty + i * 8;
        int k = k0 + tx;
        out[(size_t)n * K + k] = f2bf(tile[tx][ty + i * 8]);
    }
}

// ---------------------------------------------------------------------------
// Embedding: x[row,c] = wte[idx[row],c] + wpe[row%1024,c]   (fp32)
// ---------------------------------------------------------------------------
__global__ void embed_kernel(const int* __restrict__ idx, const float* __restrict__ wte,
                             const float* __restrict__ wpe, float* __restrict__ x) {
    int tid = blockIdx.x * 256 + threadIdx.x;      // 2048*768 total
    int row = tid / 768, c = tid - row * 768;
    int t = row & 1023;
    int tok = idx[row];
    x[tid] = wte[(size_t)tok * 768 + c] + wpe[(size_t)t * 768 + c];
}

// ---------------------------------------------------------------------------
// LayerNorm: fp32 [row,768] -> bf16 out. One block (256 thr) per row.
// ---------------------------------------------------------------------------
__global__ __launch_bounds__(256) void ln_kernel(const float* __restrict__ x,
                                                 const float* __restrict__ g,
                                                 const float* __restrict__ beta,
                                                 uint16_t* __restrict__ out) {
    int row = blockIdx.x;
    int t = threadIdx.x;
    int w = t >> 6, lane = t & 63;
    const float* xr = x + (size_t)row * 768;
    float v0 = xr[t], v1 = xr[t + 256], v2 = xr[t + 512];
    float s = v0 + v1 + v2;
    float s2 = v0 * v0 + v1 * v1 + v2 * v2;
#pragma unroll
    for (int mk = 32; mk >= 1; mk >>= 1) {
        s += __shfl_xor(s, mk, 64);
        s2 += __shfl_xor(s2, mk, 64);
    }
    __shared__ float rs[4], rq[4];
    if (lane == 0) { rs[w] = s; rq[w] = s2; }
    __syncthreads();
    float S = rs[0] + rs[1] + rs[2] + rs[3];
    float S2 = rq[0] + rq[1] + rq[2] + rq[3];
    float mean = S * (1.f / 768.f);
    float var = S2 * (1.f / 768.f) - mean * mean;
    float rinv = rsqrtf(var + 1e-5f);
    uint16_t* orow = out + (size_t)row * 768;
    orow[t]       = f2bf((v0 - mean) * rinv * g[t]       + beta[t]);
    orow[t + 256] = f2bf((v1 - mean) * rinv * g[t + 256] + beta[t + 256]);
    orow[t + 512] = f2bf((v2 - mean) * rinv * g[t + 512] + beta[t + 512]);
}

// ---------------------------------------------------------------------------
// GEMM: C[M,N] = A[M,K](bf16) @ Bt[N,K](bf16, pre-transposed) + bias.
// 128x128 tile, BK=32, 4 waves (2x2), 64x64 per wave via 4x4 mfma 16x16x32.
// Epilogues: 0=bf16 store, 1=gelu+bf16, 2=residual fp32 +=, 3=fp32 store (n<Nstore).
// ---------------------------------------------------------------------------
enum { EPI_BF16 = 0, EPI_GELU = 1, EPI_RESID = 2, EPI_F32 = 3 };

template <int EPI>
__global__ __launch_bounds__(256, 2)
void gemm128(const uint16_t* __restrict__ A, const uint16_t* __restrict__ Bt,
             const float* __restrict__ bias, uint16_t* __restrict__ Cbf,
             float* __restrict__ Cf, int M, int N, int K, int Nstore) {
    __shared__ __align__(16) uint16_t As[128][40];   // pad 8 bf16 = 16B; rowstride 80B
    __shared__ __align__(16) uint16_t Bs[128][40];
    const int bm = blockIdx.y, bn = blockIdx.x;
    const int t = threadIdx.x;
    const int w = t >> 6, lane = t & 63;
    const int wy = w >> 1, wx = w & 1;
    const int q = lane >> 4, r = lane & 15;

    floatx4 acc[4][4];
#pragma unroll
    for (int i = 0; i < 4; ++i)
#pragma unroll
        for (int j = 0; j < 4; ++j)
            acc[i][j] = (floatx4){0.f, 0.f, 0.f, 0.f};

    const size_t abase = (size_t)(bm * 128) * K;
    const size_t bbase = (size_t)(bn * 128) * K;

    for (int k0 = 0; k0 < K; k0 += 32) {
#pragma unroll
        for (int s = 0; s < 2; ++s) {
            int c = t + s * 256;
            int row = c >> 2, col = (c & 3) * 8;
            *(uint4*)&As[row][col] = *(const uint4*)(A + abase + (size_t)row * K + k0 + col);
            *(uint4*)&Bs[row][col] = *(const uint4*)(Bt + bbase + (size_t)row * K + k0 + col);
        }
        __syncthreads();
        bf16x8 fa[4], fb[4];
#pragma unroll
        for (int i = 0; i < 4; ++i) fa[i] = *(const bf16x8*)&As[wy * 64 + i * 16 + r][q * 8];
#pragma unroll
        for (int j = 0; j < 4; ++j) fb[j] = *(const bf16x8*)&Bs[wx * 64 + j * 16 + r][q * 8];
#pragma unroll
        for (int i = 0; i < 4; ++i)
#pragma unroll
            for (int j = 0; j < 4; ++j)
                acc[i][j] = __builtin_amdgcn_mfma_f32_16x16x32_bf16(fa[i], fb[j], acc[i][j], 0, 0, 0);
        __syncthreads();
    }

#pragma unroll
    for (int i = 0; i < 4; ++i) {
#pragma unroll
        for (int j = 0; j < 4; ++j) {
#pragma unroll
            for (int e = 0; e < 4; ++e) {
                int m = bm * 128 + wy * 64 + i * 16 + q * 4 + e;
                int n = bn * 128 + wx * 64 + j * 16 + r;
                float v = acc[i][j][e];
                if (bias) v += bias[n];
                if (EPI == EPI_GELU) v = 0.5f * v * (1.f + erff(v * 0.70710678118f));
                if (EPI == EPI_BF16 || EPI == EPI_GELU) {
                    Cbf[(size_t)m * N + n] = f2bf(v);
                } else if (EPI == EPI_RESID) {
                    Cf[(size_t)m * N + n] += v;
                } else {
                    if (n < Nstore) Cf[(size_t)m * Nstore + n] = v;
                }
            }
        }
    }
}

// ---------------------------------------------------------------------------
// Causal attention, one wave per (b,h,t) query row. hd=64 = wave width.
// qkv bf16 [2048, 2304] (q|k|v each 768, head-major 64). y bf16 [2048,768].
// ---------------------------------------------------------------------------
__global__ __launch_bounds__(256) void attn_kernel(const uint16_t* __restrict__ qkv,
                                                   uint16_t* __restrict__ y) {
    __shared__ float sc[4][1024];
    __shared__ float qs[4][64];
    int w = threadIdx.x >> 6, lane = threadIdx.x & 63;
    int W = blockIdx.x * 4 + w;            // 0..24575
    int bh = W >> 10;                      // 0..23
    int t = W & 1023;
    int b = bh / 12, h = bh % 12;

    const uint16_t* qrow = qkv + ((size_t)(b * 1024 + t)) * 2304 + h * 64;
    qs[w][lane] = bf2f(qrow[lane]) * 0.125f;   // fold 1/sqrt(64)
    __syncthreads();

    // Phase 1: scores. Each lane handles key j = jb*64+lane.
    int nb = (t >> 6) + 1;
    for (int jb = 0; jb < nb; ++jb) {
        int j = jb * 64 + lane;
        const uint4* kp4 = (const uint4*)(qkv + ((size_t)(b * 1024 + j)) * 2304 + 768 + h * 64);
        float s = 0.f;
#pragma unroll
        for (int q4 = 0; q4 < 8; ++q4) {
            uint4 kv4 = kp4[q4];
            uint32_t us[4] = {kv4.x, kv4.y, kv4.z, kv4.w};
#pragma unroll
            for (int c = 0; c < 4; ++c) {
                int d = q4 * 8 + c * 2;
                s += qs[w][d] * asf(us[c] << 16);
                s += qs[w][d + 1] * asf(us[c] & 0xffff0000u);
            }
        }
        sc[w][j] = (j <= t) ? s : -INFINITY;
    }
    __threadfence_block();

    // Phase 2: softmax over sc[w][0 .. nb*64)
    int nv = nb * 64;
    float mx = -INFINITY;
    for (int j = lane; j < nv; j += 64) mx = fmaxf(mx, sc[w][j]);
#pragma unroll
    for (int mk = 32; mk >= 1; mk >>= 1) mx = fmaxf(mx, __shfl_xor(mx, mk, 64));
    float l = 0.f;
    for (int j = lane; j < nv; j += 64) {
        float e = __expf(sc[w][j] - mx);
        sc[w][j] = e;
        l += e;
    }
#pragma unroll
    for (int mk = 32; mk >= 1; mk >>= 1) l += __shfl_xor(l, mk, 64);
    float inv = 1.f / l;
    __threadfence_block();

    // Phase 3: out[d] = sum_j p_j * v[j][d] ; lane = d. Coalesced v reads.
    float acc = 0.f;
    const uint16_t* vcol = qkv + (size_t)(b * 1024) * 2304 + 1536 + h * 64 + lane;
    int j = 0;
    for (; j + 4 <= t + 1; j += 4) {
        float p0 = sc[w][j], p1 = sc[w][j + 1], p2 = sc[w][j + 2], p3 = sc[w][j + 3];
        acc += p0 * bf2f(vcol[(size_t)(j + 0) * 2304]);
        acc += p1 * bf2f(vcol[(size_t)(j + 1) * 2304]);
        acc += p2 * bf2f(vcol[(size_t)(j + 2) * 2304]);
        acc += p3 * bf2f(vcol[(size_t)(j + 3) * 2304]);
    }
    for (; j <= t; ++j) acc += sc[w][j] * bf2f(vcol[(size_t)j * 2304]);
    y[((size_t)(b * 1024 + t)) * 768 + h * 64 + lane] = f2bf(acc * inv);
}

// ---------------------------------------------------------------------------
extern "C" void kernel_launch(void* const* d_in, const int* in_sizes, int n_in,
                              void* d_out, int out_size, void* d_ws, size_t ws_size,
                              hipStream_t stream) {
    (void)in_sizes; (void)n_in; (void)out_size; (void)ws_size;
    const int*   idx    = (const int*)  d_in[0];
    const float* wte    = (const float*)d_in[1];
    const float* wpe    = (const float*)d_in[2];
    const float* ln1_g  = (const float*)d_in[3];
    const float* ln1_b  = (const float*)d_in[4];
    const float* w_attn = (const float*)d_in[5];
    const float* b_attn = (const float*)d_in[6];
    const float* w_ap   = (const float*)d_in[7];
    const float* b_ap   = (const float*)d_in[8];
    const float* ln2_g  = (const float*)d_in[9];
    const float* ln2_b  = (const float*)d_in[10];
    const float* w_fc   = (const float*)d_in[11];
    const float* b_fc   = (const float*)d_in[12];
    const float* w_mp   = (const float*)d_in[13];
    const float* b_mp   = (const float*)d_in[14];
    const float* lnf_g  = (const float*)d_in[15];
    const float* lnf_b  = (const float*)d_in[16];
    const float* w_head = (const float*)d_in[17];
    float* out = (float*)d_out;

    char* p = (char*)d_ws;
    auto take = [&](size_t bytes) -> char* {
        char* r = p; p += (bytes + 255) & ~(size_t)255; return r;
    };
    float*    x     = (float*)   take((size_t)2048 * 768 * 4);
    uint16_t* h     = (uint16_t*)take((size_t)2048 * 768 * 2);
    uint16_t* qkv   = (uint16_t*)take((size_t)2048 * 2304 * 2);
    uint16_t* y     = (uint16_t*)take((size_t)2048 * 768 * 2);
    uint16_t* fca   = (uint16_t*)take((size_t)2048 * 3072 * 2);
    uint16_t* attnT = (uint16_t*)take((size_t)4 * 2304 * 768 * 2);
    uint16_t* apT   = (uint16_t*)take((size_t)4 * 768 * 768 * 2);
    uint16_t* fcT   = (uint16_t*)take((size_t)4 * 3072 * 768 * 2);
    uint16_t* mpT   = (uint16_t*)take((size_t)4 * 768 * 3072 * 2);
    uint16_t* headT = (uint16_t*)take((size_t)50304 * 768 * 2);

    dim3 tb(32, 8);
    transpose_cvt<<<dim3(2304 / 32, 768 / 32, 4), tb, 0, stream>>>(
        w_attn, attnT, 768, 2304, (size_t)768 * 2304, (size_t)2304 * 768);
    transpose_cvt<<<dim3(768 / 32, 768 / 32, 4), tb, 0, stream>>>(
        w_ap, apT, 768, 768, (size_t)768 * 768, (size_t)768 * 768);
    transpose_cvt<<<dim3(3072 / 32, 768 / 32, 4), tb, 0, stream>>>(
        w_fc, fcT, 768, 3072, (size_t)768 * 3072, (size_t)3072 * 768);
    transpose_cvt<<<dim3(768 / 32, 3072 / 32, 4), tb, 0, stream>>>(
        w_mp, mpT, 3072, 768, (size_t)3072 * 768, (size_t)768 * 3072);
    transpose_cvt<<<dim3(50304 / 32, 768 / 32, 1), tb, 0, stream>>>(
        w_head, headT, 768, 50257, 0, 0);

    embed_kernel<<<6144, 256, 0, stream>>>(idx, wte, wpe, x);

    for (int l = 0; l < 4; ++l) {
        ln_kernel<<<2048, 256, 0, stream>>>(x, ln1_g + l * 768, ln1_b + l * 768, h);
        gemm128<EPI_BF16><<<dim3(2304 / 128, 16), 256, 0, stream>>>(
            h, attnT + (size_t)l * 2304 * 768, b_attn + l * 2304, qkv, nullptr,
            2048, 2304, 768, 2304);
        attn_kernel<<<6144, 256, 0, stream>>>(qkv, y);
        gemm128<EPI_RESID><<<dim3(768 / 128, 16), 256, 0, stream>>>(
            y, apT + (size_t)l * 768 * 768, b_ap + l * 768, nullptr, x,
            2048, 768, 768, 768);
        ln_kernel<<<2048, 256, 0, stream>>>(x, ln2_g + l * 768, ln2_b + l * 768, h);
        gemm128<EPI_GELU><<<dim3(3072 / 128, 16), 256, 0, stream>>>(
            h, fcT + (size_t)l * 3072 * 768, b_fc + l * 3072, fca, nullptr,
            2048, 3072, 768, 3072);
        gemm128<EPI_RESID><<<dim3(768 / 128, 16), 256, 0, stream>>>(
            fca, mpT + (size_t)l * 768 * 3072, b_mp + l * 768, nullptr, x,
            2048, 768, 3072, 768);
    }
    ln_kernel<<<2048, 256, 0, stream>>>(x, lnf_g, lnf_b, h);
    gemm128<EPI_F32><<<dim3(50304 / 128, 16), 256, 0, stream>>>(
        h, headT, nullptr, nullptr, out, 2048, 50304, 768, 50257);
}